// Round 5
// baseline (596.759 us; speedup 1.0000x reference)
//
#include <hip/hip_runtime.h>
#include <hip/hip_bf16.h>
#include <math.h>

// Problem constants
#define B_    8
#define CDIM  512
#define HW    4096
#define CI_   64
#define MT    64            // kv rows per tile
#define NTIL  (HW/MT)       // 64 tiles

typedef __attribute__((ext_vector_type(8))) short bf16x8;
typedef __attribute__((ext_vector_type(4))) float f32x4;
typedef __attribute__((ext_vector_type(16))) float f32x16;
typedef unsigned short u16;
typedef unsigned int   u32;

// fp32 -> bf16 bits with RNE rounding
__device__ __forceinline__ u32 bfr(float f) {
  u32 x = __float_as_uint(f);
  return (x + 0x7fffu + ((x >> 16) & 1u)) >> 16;
}
// packed 2xf32 -> bf16x2 (RNE) via HW instruction
__device__ __forceinline__ u32 cvtpk(float a, float b) {
  u32 r;
  asm("v_cvt_pk_bf16_f32 %0, %1, %2" : "=v"(r) : "v"(a), "v"(b));
  return r;
}

// ---------------- cast fp32 -> bf16 (weights) ----------------
__global__ void cast_bf16(const float* __restrict__ in, u16* __restrict__ out, int n) {
  int i = blockIdx.x * 256 + threadIdx.x;
  if (i < n) out[i] = (u16)bfr(in[i]);
}

// ---------------- transpose+cast: X [C,HW] f32 -> Xt [HW,C] bf16, per batch ----------------
__global__ void transpose_cast(const float* __restrict__ X, u16* __restrict__ Xt) {
  __shared__ float tile[32][33];
  const int n0 = blockIdx.x * 32, c0 = blockIdx.y * 32;
  const float* Xb = X + (size_t)blockIdx.z * CDIM * HW;
  u16* Xtb = Xt + (size_t)blockIdx.z * HW * CDIM;
  const int tx = threadIdx.x, ty = threadIdx.y; // block (32,8)
#pragma unroll
  for (int i = 0; i < 4; ++i)
    tile[ty + 8 * i][tx] = Xb[(size_t)(c0 + ty + 8 * i) * HW + n0 + tx];
  __syncthreads();
#pragma unroll
  for (int i = 0; i < 4; ++i)
    Xtb[(size_t)(n0 + ty + 8 * i) * CDIM + c0 + tx] = (u16)bfr(tile[tx][ty + 8 * i]);
}

// ---------------- NT GEMM: D[i,j] = (sum_k A[i,k]*B[j,k] + bias)*alpha, bf16 in/out ----------------
__global__ __launch_bounds__(256) void gemm_nt(
    const u16* __restrict__ A, const u16* __restrict__ Bm, u16* __restrict__ D,
    const float* __restrict__ bias, int biasRow, float alpha,
    int lda, int ldb, int ldd, long aBatch, long bBatch, long dBatch, int Kd)
{
  const int tid = threadIdx.x, wid = tid >> 6, lane = tid & 63;
  const int lr = lane & 15, lg = lane >> 4;
  const int i0 = blockIdx.x * 128 + wid * 32;
  const int j0 = blockIdx.y * 64;
  const u16* Ab = A + blockIdx.z * aBatch;
  const u16* Bb = Bm + blockIdx.z * bBatch;
  f32x4 acc[2][4];
#pragma unroll
  for (int rt = 0; rt < 2; ++rt)
#pragma unroll
    for (int ct = 0; ct < 4; ++ct) acc[rt][ct] = (f32x4){0.f, 0.f, 0.f, 0.f};

#pragma unroll 4
  for (int k0 = 0; k0 < Kd; k0 += 32) {
    bf16x8 af[2], bf[4];
#pragma unroll
    for (int rt = 0; rt < 2; ++rt)
      af[rt] = *(const bf16x8*)(Ab + (size_t)(i0 + rt * 16 + lr) * lda + k0 + lg * 8);
#pragma unroll
    for (int ct = 0; ct < 4; ++ct)
      bf[ct] = *(const bf16x8*)(Bb + (size_t)(j0 + ct * 16 + lr) * ldb + k0 + lg * 8);
#pragma unroll
    for (int rt = 0; rt < 2; ++rt)
#pragma unroll
      for (int ct = 0; ct < 4; ++ct)
        acc[rt][ct] = __builtin_amdgcn_mfma_f32_16x16x32_bf16(af[rt], bf[ct], acc[rt][ct], 0, 0, 0);
  }

  u16* Db = D + blockIdx.z * dBatch;
#pragma unroll
  for (int rt = 0; rt < 2; ++rt)
#pragma unroll
    for (int ct = 0; ct < 4; ++ct)
#pragma unroll
      for (int r = 0; r < 4; ++r) {
        int i = i0 + rt * 16 + lg * 4 + r;
        int j = j0 + ct * 16 + lr;
        float v = (acc[rt][ct][r] + (biasRow ? bias[i] : bias[j])) * alpha;
        Db[(size_t)i * ldd + j] = (u16)bfr(v);
      }
}

// ---------------- fused flash attention + gamma*attn + value ----------------
// No max-tracking (|S| ~ 2 << 88): P = exp(S), l = sum exp(S).
// Block = 4 waves = 64 q-rows x FULL C=512 (no c-duplication of QK/exp).
// QK: waves split the 64x64 S-tile into 32x32 chunks (mq=wid&1, nq=wid>>1);
//     P written bf16-packed to swizzled LDS (dbuf), ONE barrier/tile.
// PV: wave = c-quarter (cg=wid): acc = 2ng x 4ct x f32x16 = 128 VGPR.
// K and V fragments read DIRECT from global (L1/L2-resident row-gather;
// 4 kk-instrs share each 128B line via L1). K frags for t+1 and V frags
// prefetched into registers during phase B.
__global__ __launch_bounds__(256, 2) void flash_attn(
    const u16* __restrict__ Q, const u16* __restrict__ K, const u16* __restrict__ V,
    const float* __restrict__ value, const float* __restrict__ gammap, float* __restrict__ out)
{
  __shared__ __align__(16) char smem[18176];
  // [0,16384): Ps dbuf = 2 x [n=64 rows][64 u16 = 8 chunks of 16B], chunk ^= (n&7)
  // epilogue reuse: [0,17408) per-wave transpose scratch; [17408,17920) lred

  const int b  = blockIdx.x & 7;
  const int nb = blockIdx.x >> 3;
  const int tid = threadIdx.x, wid = tid >> 6, lane = tid & 63;
  const int l31 = lane & 31, h = lane >> 5;
  const int mq = wid & 1, nq = wid >> 1;   // QK chunk role
  const int cg = wid;                       // PV c-quarter role
  const int nb0 = nb * 64;

  const u16* Qb = Q + (size_t)b * HW * CI_;
  const u16* Kb = K + (size_t)b * HW * CI_;
  const u16* Vb = V + (size_t)b * CDIM * HW;

  // Q frags (B-op of swapped QK^T): col n = nb0 + nq*32 + l31, k = kk*16 + h*8 + j
  bf16x8 qf[4];
  {
    const u16* qp = Qb + (size_t)(nb0 + nq * 32 + l31) * CI_ + h * 8;
#pragma unroll
    for (int kk = 0; kk < 4; ++kk) qf[kk] = *(const bf16x8*)(qp + kk * 16);
  }

  // K frags (A-op): row m = t*64 + mq*32 + l31, same k mapping; prefetched per tile
  const u16* kp = Kb + (size_t)(mq * 32 + l31) * CI_ + h * 8;
  bf16x8 kf[4];
#pragma unroll
  for (int kk = 0; kk < 4; ++kk) kf[kk] = *(const bf16x8*)(kp + kk * 16);  // t=0

  // V per-lane base: c = cg*128 + ct*32 + l31, m-offset h*8
  const u16* vp = Vb + (size_t)(cg * 128 + l31) * HW + h * 8;
  bf16x8 vfr0[2][4];   // ct 0,1 of this wave's quarter (prefetched)
#pragma unroll
  for (int c2 = 0; c2 < 2; ++c2)
#pragma unroll
    for (int kk = 0; kk < 4; ++kk)
      vfr0[c2][kk] = *(const bf16x8*)(vp + (size_t)(c2 * 32) * HW + kk * 16);  // t=0

  f32x16 acc[2][4];
#pragma unroll
  for (int ng = 0; ng < 2; ++ng)
#pragma unroll
    for (int ct = 0; ct < 4; ++ct)
#pragma unroll
      for (int i = 0; i < 16; ++i) acc[ng][ct][i] = 0.f;
  float lp = 0.f;

  for (int t = 0; t < NTIL; ++t) {
    char* PsC = smem + (t & 1) * 8192;

    // ---- phase A: QK chunk + exp + packed P write ----
    f32x16 st;
#pragma unroll
    for (int i = 0; i < 16; ++i) st[i] = 0.f;
#pragma unroll
    for (int kk = 0; kk < 4; ++kk)
      st = __builtin_amdgcn_mfma_f32_32x32x16_bf16(kf[kk], qf[kk], st, 0, 0, 0);

    float p[16]; float rs = 0.f;
#pragma unroll
    for (int r = 0; r < 16; ++r) { p[r] = __expf(st[r]); rs += p[r]; }
    lp += rs;   // covers m-strip mq, half h, rows n = nq*32 + l31

    {
      const int nrow = nq * 32 + l31;
      char* pw = PsC + nrow * 128 + 8 * h;
#pragma unroll
      for (int g = 0; g < 4; ++g) {   // m = mq*32 + g*8 + 4h + 0..3 -> chunk 4mq+g
        uint2 w;
        w.x = cvtpk(p[4 * g], p[4 * g + 1]);
        w.y = cvtpk(p[4 * g + 2], p[4 * g + 3]);
        *(uint2*)(pw + (((4 * mq + g) ^ (nrow & 7)) * 16)) = w;
      }
    }
    __syncthreads();   // single barrier: Ps[par] complete (dbuf covers the skew)

    // ---- phase B: PV over full m=64 for this wave's 128 c ----
    const size_t mt = (size_t)t * MT;
    bf16x8 vfr1[2][4];   // ct 2,3
#pragma unroll
    for (int c2 = 0; c2 < 2; ++c2)
#pragma unroll
      for (int kk = 0; kk < 4; ++kk)
        vfr1[c2][kk] = *(const bf16x8*)(vp + (size_t)(64 + c2 * 32) * HW + mt + kk * 16);

    bf16x8 paf[2][4];
#pragma unroll
    for (int ng = 0; ng < 2; ++ng) {
      const int prow = ng * 32 + l31;
      const char* prp = PsC + prow * 128;
#pragma unroll
      for (int kk = 0; kk < 4; ++kk)
        paf[ng][kk] = *(const bf16x8*)(prp + (((2 * kk + h) ^ (prow & 7)) * 16));
    }

    __builtin_amdgcn_s_setprio(1);
#pragma unroll
    for (int kk = 0; kk < 4; ++kk)
#pragma unroll
      for (int c2 = 0; c2 < 2; ++c2) {
        acc[0][c2] = __builtin_amdgcn_mfma_f32_32x32x16_bf16(vfr0[c2][kk], paf[0][kk], acc[0][c2], 0, 0, 0);
        acc[1][c2] = __builtin_amdgcn_mfma_f32_32x32x16_bf16(vfr0[c2][kk], paf[1][kk], acc[1][c2], 0, 0, 0);
      }
    __builtin_amdgcn_s_setprio(0);

    if (t + 1 < NTIL) {   // K frags for t+1 (latency hidden by second MFMA batch)
      const u16* kn = kp + (size_t)(t + 1) * MT * CI_;
#pragma unroll
      for (int kk = 0; kk < 4; ++kk) kf[kk] = *(const bf16x8*)(kn + kk * 16);
    }

    __builtin_amdgcn_s_setprio(1);
#pragma unroll
    for (int kk = 0; kk < 4; ++kk)
#pragma unroll
      for (int c2 = 0; c2 < 2; ++c2) {
        acc[0][2 + c2] = __builtin_amdgcn_mfma_f32_32x32x16_bf16(vfr1[c2][kk], paf[0][kk], acc[0][2 + c2], 0, 0, 0);
        acc[1][2 + c2] = __builtin_amdgcn_mfma_f32_32x32x16_bf16(vfr1[c2][kk], paf[1][kk], acc[1][2 + c2], 0, 0, 0);
      }
    __builtin_amdgcn_s_setprio(0);

    if (t + 1 < NTIL) {   // V frags ct 0,1 for t+1 (covered by A(t+1) + barrier)
#pragma unroll
      for (int c2 = 0; c2 < 2; ++c2)
#pragma unroll
        for (int kk = 0; kk < 4; ++kk)
          vfr0[c2][kk] = *(const bf16x8*)(vp + (size_t)(c2 * 32) * HW + mt + 64 + kk * 16);
    }
  }

  // ---- epilogue ----
  __syncthreads();                       // all Ps reads done; reuse smem
  lp += __shfl_xor(lp, 32);              // combine h halves
  float* lred = (float*)(smem + 17408);  // [nq*2+mq][32]
  if (lane < 32) lred[(nq * 2 + mq) * 32 + l31] = lp;
  __syncthreads();

  const float g = gammap[0];
  float* Tls = (float*)(smem + wid * 4352);   // per-wave 32c x 33n f32
  const size_t obase = (size_t)b * CDIM * HW;
#pragma unroll
  for (int ng = 0; ng < 2; ++ng) {
    const float ri = g / (lred[(ng * 2) * 32 + l31] + lred[(ng * 2 + 1) * 32 + l31]);
#pragma unroll
    for (int ct = 0; ct < 4; ++ct) {
      // acc lane l31 = n-col (ng*32+l31), reg r = c-row; transpose via LDS
#pragma unroll
      for (int r = 0; r < 16; ++r) {
        int cc = (r & 3) + 8 * (r >> 2) + 4 * h;
        Tls[cc * 33 + l31] = acc[ng][ct][r] * ri;
      }
#pragma unroll
      for (int pp = 0; pp < 16; ++pp) {
        float v = Tls[l31 * 33 + 2 * pp + h];
        int n = nb0 + ng * 32 + 2 * pp + h;
        int c = cg * 128 + ct * 32 + l31;
        size_t idx = obase + (size_t)n * CDIM + c;
        out[idx] = v + value[idx];
      }
    }
  }
}

extern "C" void kernel_launch(void* const* d_in, const int* in_sizes, int n_in,
                              void* d_out, int out_size, void* d_ws, size_t ws_size,
                              hipStream_t stream) {
  const float* query = (const float*)d_in[0];
  const float* key   = (const float*)d_in[1];
  const float* value = (const float*)d_in[2];
  const float* Wq    = (const float*)d_in[3];
  const float* bq    = (const float*)d_in[4];
  const float* Wk    = (const float*)d_in[5];
  const float* bk    = (const float*)d_in[6];
  const float* Wv    = (const float*)d_in[7];
  const float* bv    = (const float*)d_in[8];
  const float* gamma = (const float*)d_in[9];

  char* ws = (char*)d_ws;
  u16* XT  = (u16*)(ws);               // 33,554,432 B  [B,HW,C] bf16
  u16* Qb  = (u16*)(ws + 33554432);    //  4,194,304 B  [B,HW,CI]
  u16* Kb  = (u16*)(ws + 37748736);    //  4,194,304 B  [B,HW,CI]
  u16* Vb  = (u16*)(ws + 41943040);    // 33,554,432 B  [B,C,HW]
  u16* WQb = (u16*)(ws + 75497472);    //     65,536 B
  u16* WKb = (u16*)(ws + 75563008);    //     65,536 B
  u16* WVb = (u16*)(ws + 75628544);    //    524,288 B

  cast_bf16<<<(32768 + 255) / 256, 256, 0, stream>>>(Wq, WQb, 32768);
  cast_bf16<<<(32768 + 255) / 256, 256, 0, stream>>>(Wk, WKb, 32768);
  cast_bf16<<<(262144 + 255) / 256, 256, 0, stream>>>(Wv, WVb, 262144);

  dim3 tgrid(HW / 32, CDIM / 32, B_);
  dim3 tblk(32, 8);

  // Q = (query^T Wq^T + bq) * (1/8)   -> [B,HW,CI]
  transpose_cast<<<tgrid, tblk, 0, stream>>>(query, XT);
  gemm_nt<<<dim3(HW / 128, 1, B_), 256, 0, stream>>>(
      XT, WQb, Qb, bq, 0, 0.125f, CDIM, CDIM, CI_,
      (long)HW * CDIM, 0L, (long)HW * CI_, CDIM);

  // K = key^T Wk^T + bk               -> [B,HW,CI]
  transpose_cast<<<tgrid, tblk, 0, stream>>>(key, XT);
  gemm_nt<<<dim3(HW / 128, 1, B_), 256, 0, stream>>>(
      XT, WKb, Kb, bk, 0, 1.0f, CDIM, CDIM, CI_,
      (long)HW * CDIM, 0L, (long)HW * CI_, CDIM);

  // V^T = Wv (value^T)^T + bv  stored [B, C, HW]
  transpose_cast<<<tgrid, tblk, 0, stream>>>(value, XT);
  gemm_nt<<<dim3(CDIM / 128, HW / 64, B_), 256, 0, stream>>>(
      WVb, XT, Vb, bv, 1, 1.0f, CDIM, CDIM, HW,
      0L, (long)HW * CDIM, (long)CDIM * HW, CDIM);

  // Fused flash attention + epilogue
  flash_attn<<<512, 256, 0, stream>>>(Qb, Kb, Vb, value, gamma, (float*)d_out);
}